// Round 6
// baseline (1549.918 us; speedup 1.0000x reference)
//
#include <hip/hip_runtime.h>
#include <math.h>

// ---------------------------------------------------------------------------
// VQ-VAE 3D forward, round 6.
// Diagnosis chain: round-2 conv2 VALU-busy = 69us (1.26x FMA floor, clean);
// rounds 3-5 = 218us (4.0x) regardless of VGPR budget => inflation is SGPR
// lane-spill (v_writelane/readlane = VALU) caused by s_load_dwordx16 weight
// tuples exhausting the SGPR file. Fix: weights repacked on-device into
// [ci][t16][oc][8] — 4-float groups 16B-aligned with 16B gaps, so the
// compiler can only form s_load_dwordx4 (round-2's measured-clean shape).
// Conv: TZ=2 x OCG=8 fat threads, padded unconditional ld4 x-loads.
// ConvT: octet-per-thread x OCG=4, per-(kz,ky,c) dwordx4 weights.
// oc-groups folded into low bits of blockIdx.x for L2 tile locality.
// ---------------------------------------------------------------------------

__device__ __forceinline__ float4 ld4(const float* p) {
  float4 q; __builtin_memcpy(&q, p, 16); return q;
}
struct F3 { float x, y, z; };
__device__ __forceinline__ F3 ld3(const float* p) {
  F3 q; __builtin_memcpy(&q, p, 12); return q;
}
__device__ __forceinline__ void st4(float* p, float4 v) {
  __builtin_memcpy(p, &v, 16);
}

#define WAVES_HINT __attribute__((amdgpu_waves_per_eu(2, 4)))

// ---------------- weight repack: -> [ci][t16][oc][8] (4 used + 4 pad) -------
// FWD: src w[oc][ci][t] (OIDHW). !FWD: src w[ci][oc][t] (PyTorch convT).
template<int CIN, int COUT, bool FWD>
__global__ __launch_bounds__(256) void k_repack(const float* __restrict__ w,
                                                float* __restrict__ dst) {
  const int idx = blockIdx.x * 256 + threadIdx.x;
  if (idx >= CIN * COUT * 64) return;
  const int t  = idx & 63;
  const int oc = (idx >> 6) % COUT;
  const int ci = idx / (64 * COUT);
  const float v = FWD ? w[((size_t)oc * CIN + ci) * 64 + t]
                      : w[((size_t)ci * COUT + oc) * 64 + t];
  dst[(((size_t)ci * 16 + (t >> 2)) * COUT + oc) * 8 + (t & 3)] = v;
}

// ---------------- halo zeroing for padded buffers ---------------------------
template<int S, int D, int NCH>
__global__ __launch_bounds__(256) void k_zhalo(float* __restrict__ buf) {
  const int vol = S * S * S;
  const long long idx = (long long)blockIdx.x * 256 + threadIdx.x;
  if (idx >= (long long)NCH * vol) return;
  const int r = (int)(idx % vol);
  const int z = r / (S * S), y = (r / S) % S, x = r % S;
  if (z < 1 || z > D || y < 1 || y > D || x < 1 || x > D) buf[idx] = 0.0f;
}

// ---------------- forward conv (k=4,s=2,p=1) --------------------------------
// Thread: 8x8x4 spatial block, TZ z-outputs (stride 4), OCG channels.
// Weights via repacked wfp (dwordx4-only scalar loads).
template<int CIN, int COUT, int DIN, int DOUT, int OCG, int TZ, bool RELU,
         bool INP, int SIN, bool OUTP, int SOUT, int NG>
__global__ __launch_bounds__(256) WAVES_HINT
void k_conv(const float* __restrict__ xin, const float* __restrict__ wfp,
            const float* __restrict__ bias, float* __restrict__ out) {
  constexpr int NBX = DOUT / 8, NBY = DOUT / 8, NBZ = DOUT / (4 * TZ);
  constexpr size_t VIN  = INP  ? (size_t)SIN * SIN * SIN : (size_t)DIN * DIN * DIN;
  constexpr size_t VOUT = OUTP ? (size_t)SOUT * SOUT * SOUT : (size_t)DOUT * DOUT * DOUT;
  const int tid = threadIdx.x;
  const int tx = tid & 7, ty = (tid >> 3) & 7, tz = tid >> 6;
  int bb = blockIdx.x;
  const int g  = bb % NG;  bb /= NG;   // oc-group in LOW bits -> L2 locality
  const int gx = bb % NBX; bb /= NBX;
  const int gy = bb % NBY; bb /= NBY;
  const int gz = bb % NBZ; bb /= NBZ;
  const int b = bb;
  const int oc0 = g * OCG;
  const int ow = gx * 8 + tx, oh = gy * 8 + ty, od0 = gz * (4 * TZ) + tz;

  float acc[TZ][OCG];
#pragma unroll
  for (int j = 0; j < TZ; ++j)
#pragma unroll
    for (int c = 0; c < OCG; ++c) acc[j][c] = 0.0f;

#pragma unroll 1
  for (int ci = 0; ci < CIN; ++ci) {
    const float* xb  = xin + (size_t)(b * CIN + ci) * VIN;
    const float* wci = wfp + (size_t)ci * (16 * COUT * 8) + (size_t)oc0 * 8;
#pragma unroll 1
    for (int t16 = 0; t16 < 16; ++t16) {   // t16 = kd*4 + kh
      float4 q[TZ];
      if (INP) {
        // padded coords: z = od*2+kd, y = oh*2+kh, x = ow*2 (always valid)
        const int zp = od0 * 2 + (t16 >> 2);
        const int yp = oh * 2 + (t16 & 3);
        const float* r0 = xb + ((size_t)zp * SIN + yp) * SIN + ow * 2;
#pragma unroll
        for (int j = 0; j < TZ; ++j) q[j] = ld4(r0 + (size_t)j * 8 * SIN * SIN);
      } else {
        const int y  = oh * 2 - 1 + (t16 & 3);
        const int x0 = ow * 2 - 1;
        const bool vy = (unsigned)y < (unsigned)DIN;
#pragma unroll
        for (int j = 0; j < TZ; ++j) {
          const int z = od0 * 2 - 1 + (t16 >> 2) + j * 8;
          const bool vz = vy && ((unsigned)z < (unsigned)DIN);
          const float* xr = xb + ((size_t)z * DIN + y) * DIN + x0;
          q[j].x = (vz && (unsigned)(x0 + 0) < (unsigned)DIN) ? xr[0] : 0.0f;
          q[j].y = (vz && (unsigned)(x0 + 1) < (unsigned)DIN) ? xr[1] : 0.0f;
          q[j].z = (vz && (unsigned)(x0 + 2) < (unsigned)DIN) ? xr[2] : 0.0f;
          q[j].w = (vz && (unsigned)(x0 + 3) < (unsigned)DIN) ? xr[3] : 0.0f;
        }
      }
      const float* wt16 = wci + (size_t)t16 * (COUT * 8);
#pragma unroll
      for (int c = 0; c < OCG; ++c) {
        const float4 w4 = ld4(wt16 + c * 8);   // uniform -> s_load_dwordx4 only
#pragma unroll
        for (int j = 0; j < TZ; ++j) {
          acc[j][c] = fmaf(q[j].x, w4.x, acc[j][c]);
          acc[j][c] = fmaf(q[j].y, w4.y, acc[j][c]);
          acc[j][c] = fmaf(q[j].z, w4.z, acc[j][c]);
          acc[j][c] = fmaf(q[j].w, w4.w, acc[j][c]);
        }
      }
    }
  }

#pragma unroll
  for (int c = 0; c < OCG; ++c) {
    const float bv = bias[oc0 + c];
#pragma unroll
    for (int j = 0; j < TZ; ++j) {
      float v = acc[j][c] + bv;
      if (RELU) v = fmaxf(v, 0.0f);
      const int od = od0 + j * 4;
      if (OUTP)
        out[(size_t)(b * COUT + oc0 + c) * VOUT
            + ((size_t)(od + 1) * SOUT + (oh + 1)) * SOUT + (ow + 1)] = v;
      else
        out[(size_t)(b * COUT + oc0 + c) * VOUT
            + ((size_t)od * DOUT + oh) * DOUT + ow] = v;
    }
  }
}

// ---------------- transposed conv (k=4,s=2,p=1), octet-per-thread -----------
// Weights via repacked wtp: per (kz,ky,c) one dwordx4 (kx 0..3).
// Tap->parity map: k odd -> p=0; k even -> p=1; d = (3-k+p)/2.
template<int CIN, int COUT, int DIN, int OCG, int EPI, int SIN,
         bool OUTP, int SOUT, int NG>
__global__ __launch_bounds__(256) WAVES_HINT
void k_convt(const float* __restrict__ xin, const float* __restrict__ wtp,
             const float* __restrict__ bias, float* __restrict__ out) {
  constexpr int DOUT = 2 * DIN, NBX = DIN / 8, NBY = DIN / 8, NBZ = DIN / 4;
  constexpr size_t VIN  = (size_t)SIN * SIN * SIN;
  constexpr size_t VOUT = OUTP ? (size_t)SOUT * SOUT * SOUT
                               : (size_t)DOUT * DOUT * DOUT;
  const int tid = threadIdx.x;
  const int tx = tid & 7, ty = (tid >> 3) & 7, tz = tid >> 6;
  int bb = blockIdx.x;
  const int g  = bb % NG;  bb /= NG;
  const int gx = bb % NBX; bb /= NBX;
  const int gy = bb % NBY; bb /= NBY;
  const int gz = bb % NBZ; bb /= NBZ;
  const int b = bb;
  const int oc0 = g * OCG;
  const int mx = gx * 8 + tx, my = gy * 8 + ty, mz = gz * 4 + tz;

  float acc[8][OCG];
#pragma unroll
  for (int p = 0; p < 8; ++p)
#pragma unroll
    for (int c = 0; c < OCG; ++c) acc[p][c] = 0.0f;

#pragma unroll 1
  for (int ci = 0; ci < CIN; ++ci) {
    const float* xb = xin + (size_t)(b * CIN + ci) * VIN
                          + ((size_t)mz * SIN + my) * SIN + mx;
    float xn[3][3][3];
#pragma unroll
    for (int dz = 0; dz < 3; ++dz)
#pragma unroll
      for (int dy = 0; dy < 3; ++dy) {
        const F3 t = ld3(xb + ((size_t)dz * SIN + dy) * SIN);
        xn[dz][dy][0] = t.x; xn[dz][dy][1] = t.y; xn[dz][dy][2] = t.z;
      }
    const float* wci = wtp + (size_t)ci * (16 * COUT * 8) + (size_t)oc0 * 8;
#pragma unroll
    for (int kz = 0; kz < 4; ++kz) {
      const int pz = 1 - (kz & 1), dz = (3 - kz + pz) >> 1;
#pragma unroll
      for (int ky = 0; ky < 4; ++ky) {
        const int py = 1 - (ky & 1), dy = (3 - ky + py) >> 1;
        const float* wrow = wci + (size_t)(kz * 4 + ky) * (COUT * 8);
#pragma unroll
        for (int c = 0; c < OCG; ++c) {
          const float4 w4 = ld4(wrow + c * 8);   // s_load_dwordx4, unmergeable
#pragma unroll
          for (int kx = 0; kx < 4; ++kx) {
            const int px = 1 - (kx & 1), dx = (3 - kx + px) >> 1;
            const int p = (pz * 2 + py) * 2 + px;
            const float wv = (kx == 0) ? w4.x : (kx == 1) ? w4.y
                           : (kx == 2) ? w4.z : w4.w;
            acc[p][c] = fmaf(xn[dz][dy][dx], wv, acc[p][c]);
          }
        }
      }
    }
  }

#pragma unroll
  for (int c = 0; c < OCG; ++c) {
    const float bv = bias[oc0 + c];
#pragma unroll
    for (int p = 0; p < 8; ++p) {
      const int pz = p >> 2, py = (p >> 1) & 1, px = p & 1;
      float v = acc[p][c] + bv;
      if (EPI == 1) v = fmaxf(v, 0.0f);
      if (EPI == 2) v = 1.0f / (1.0f + expf(-v));
      if (OUTP)
        out[(size_t)(b * COUT + oc0 + c) * VOUT
            + ((size_t)(2 * mz + pz + 1) * SOUT + (2 * my + py + 1)) * SOUT
            + (2 * mx + px + 1)] = v;
      else
        out[(size_t)(b * COUT + oc0 + c) * VOUT
            + ((size_t)(2 * mz + pz) * DOUT + (2 * my + py)) * DOUT
            + (2 * mx + px)] = v;
    }
  }
}

// ---------------- convT3 (16->1): double-octet thread + sigmoid -------------
// x: padded [4,16,68^3]; thread owns m-positions (mxA, mxA+1) -> 16 outputs.
__global__ __launch_bounds__(256) WAVES_HINT
void k_convt3o(const float* __restrict__ xin, const float* __restrict__ wtp,
               const float* __restrict__ bias, float* __restrict__ out) {
  constexpr int SIN = 68;
  constexpr size_t VIN = (size_t)SIN * SIN * SIN;
  const int tid = threadIdx.x;
  const int tx = tid & 7, ty = (tid >> 3) & 7, tz = tid >> 6;
  int bb = blockIdx.x;
  const int gx = bb % 4;  bb /= 4;
  const int gy = bb % 8;  bb /= 8;
  const int gz = bb % 16; bb /= 16;
  const int b = bb;
  const int mx = gx * 16 + tx * 2, my = gy * 8 + ty, mz = gz * 4 + tz;

  float accA[8], accB[8];
#pragma unroll
  for (int p = 0; p < 8; ++p) { accA[p] = 0.0f; accB[p] = 0.0f; }

#pragma unroll 1
  for (int ci = 0; ci < 16; ++ci) {
    const float* xb = xin + (size_t)(b * 16 + ci) * VIN
                          + ((size_t)mz * SIN + my) * SIN + mx;
    float xn[3][3][4];
#pragma unroll
    for (int dz = 0; dz < 3; ++dz)
#pragma unroll
      for (int dy = 0; dy < 3; ++dy) {
        const float4 t = ld4(xb + ((size_t)dz * SIN + dy) * SIN);
        xn[dz][dy][0] = t.x; xn[dz][dy][1] = t.y;
        xn[dz][dy][2] = t.z; xn[dz][dy][3] = t.w;
      }
    const float* wci = wtp + (size_t)ci * (16 * 8);   // COUT=1
#pragma unroll
    for (int kz = 0; kz < 4; ++kz) {
      const int pz = 1 - (kz & 1), dz = (3 - kz + pz) >> 1;
#pragma unroll
      for (int ky = 0; ky < 4; ++ky) {
        const int py = 1 - (ky & 1), dy = (3 - ky + py) >> 1;
        const float4 w4 = ld4(wci + (kz * 4 + ky) * 8);
#pragma unroll
        for (int kx = 0; kx < 4; ++kx) {
          const int px = 1 - (kx & 1), dx = (3 - kx + px) >> 1;
          const int p = (pz * 2 + py) * 2 + px;
          const float wv = (kx == 0) ? w4.x : (kx == 1) ? w4.y
                         : (kx == 2) ? w4.z : w4.w;
          accA[p] = fmaf(xn[dz][dy][dx],     wv, accA[p]);
          accB[p] = fmaf(xn[dz][dy][dx + 1], wv, accB[p]);
        }
      }
    }
  }

  const float bv = bias[0];
#pragma unroll
  for (int pz = 0; pz < 2; ++pz)
#pragma unroll
    for (int py = 0; py < 2; ++py) {
      const int p0 = (pz * 2 + py) * 2;
      float4 v;
      v.x = 1.0f / (1.0f + expf(-(accA[p0]     + bv)));
      v.y = 1.0f / (1.0f + expf(-(accA[p0 + 1] + bv)));
      v.z = 1.0f / (1.0f + expf(-(accB[p0]     + bv)));
      v.w = 1.0f / (1.0f + expf(-(accB[p0 + 1] + bv)));
      st4(out + (size_t)b * 2097152
              + ((size_t)(2 * mz + pz) * 128 + (2 * my + py)) * 128 + 2 * mx, v);
    }
}

// ---------------- VQ: argmin over 512 codes, gather codebook ----------------
__global__ __launch_bounds__(256) void k_vq(const float* __restrict__ ze,
                                            const float* __restrict__ cb,
                                            float* __restrict__ quant,
                                            float* __restrict__ quantp) {
  __shared__ float ct[64 * 65];
  __shared__ float zs[4][64];
  __shared__ int   bis[4];
  const int tid  = threadIdx.x;
  const int lane = tid & 63;
  const int wv   = tid >> 6;
  const int p0 = blockIdx.x * 4;
  const int b  = p0 >> 12;
  const int n0 = p0 & 4095;

  {
    const int c = tid >> 2, j = tid & 3;
    zs[j][c] = ze[((size_t)(b * 64 + c) << 12) + n0 + j];
  }

  float best = 3.4e38f;
  int bi = 0;
#pragma unroll 1
  for (int ch = 0; ch < 8; ++ch) {
    __syncthreads();
    for (int i = tid; i < 4096; i += 256) {
      const int r = i >> 6, c = i & 63;
      ct[r * 65 + c] = cb[((ch * 64 + r) << 6) + c];
    }
    __syncthreads();
    float d = 0.0f;
#pragma unroll 8
    for (int c = 0; c < 64; ++c) {
      const float t = zs[wv][c] - ct[lane * 65 + c];
      d = fmaf(t, t, d);
    }
    const int k = ch * 64 + lane;
    if (d < best) { best = d; bi = k; }
  }
#pragma unroll
  for (int off = 32; off > 0; off >>= 1) {
    const float ob = __shfl_down(best, off);
    const int   oi = __shfl_down(bi, off);
    if (ob < best || (ob == best && oi < bi)) { best = ob; bi = oi; }
  }
  if (lane == 0) bis[wv] = bi;
  __syncthreads();
  {
    const int c = tid >> 2, j = tid & 3;
    const float val = cb[(bis[j] << 6) + c];
    const int n = n0 + j;
    quant[((size_t)(b * 64 + c) << 12) + n] = val;
    const int zz = n >> 8, yy = (n >> 4) & 15, xx = n & 15;
    quantp[(size_t)(b * 64 + c) * 8000
           + ((size_t)(zz + 1) * 20 + (yy + 1)) * 20 + (xx + 1)] = val;
  }
}

// ---------------------------------------------------------------------------
extern "C" void kernel_launch(void* const* d_in, const int* in_sizes, int n_in,
                              void* d_out, int out_size, void* d_ws, size_t ws_size,
                              hipStream_t stream) {
  const float* x   = (const float*)d_in[0];
  const float* w1  = (const float*)d_in[1];
  const float* b1  = (const float*)d_in[2];
  const float* w2  = (const float*)d_in[3];
  const float* b2  = (const float*)d_in[4];
  const float* w3  = (const float*)d_in[5];
  const float* b3  = (const float*)d_in[6];
  const float* cb  = (const float*)d_in[7];
  const float* dw1 = (const float*)d_in[8];
  const float* db1 = (const float*)d_in[9];
  const float* dw2 = (const float*)d_in[10];
  const float* db2 = (const float*)d_in[11];
  const float* dw3 = (const float*)d_in[12];
  const float* db3 = (const float*)d_in[13];

  float* outf  = (float*)d_out;
  float* xhat  = outf;               // [4,1,128^3]
  float* quant = outf + 8388608;     // [4,64,16^3]
  float* ze    = outf + 9437184;     // [4,64,16^3]

  // workspace layout
  float* regA = (float*)d_ws;                 // 64 x 68^3   (y1, then d2)
  float* regB = regA + (size_t)64 * 68 * 68 * 68;   // 128 x 36^3 (y2, then d1)
  float* regC = regB + (size_t)128 * 36 * 36 * 36;  // 256 x 20^3 (quantp)
  float* w1p = regC + (size_t)256 * 20 * 20 * 20;
  float* w2p = w1p + 2048;      // 16*32*128
  float* w3p = w2p + 65536;     // 32*64*128
  float* t1p = w3p + 262144;    // 64*32*128
  float* t2p = t1p + 262144;    // 32*16*128
  float* t3p = t2p + 65536;     // 16*1*128

  // weight repacks (tiny) + halo zeroing (ws re-poisoned every launch)
  k_repack<1, 16, true ><<<4, 256, 0, stream>>>(w1, w1p);
  k_repack<16, 32, true ><<<128, 256, 0, stream>>>(w2, w2p);
  k_repack<32, 64, true ><<<512, 256, 0, stream>>>(w3, w3p);
  k_repack<64, 32, false><<<512, 256, 0, stream>>>(dw1, t1p);
  k_repack<32, 16, false><<<128, 256, 0, stream>>>(dw2, t2p);
  k_repack<16, 1, false><<<4, 256, 0, stream>>>(dw3, t3p);
  k_zhalo<68, 64, 64><<<78608, 256, 0, stream>>>(regA);
  k_zhalo<36, 32, 128><<<23328, 256, 0, stream>>>(regB);
  k_zhalo<20, 16, 256><<<8000, 256, 0, stream>>>(regC);

  // encoder
  k_conv<1, 16, 128, 64, 16, 2, true, false, 0, true, 68, 1>
      <<<2048, 256, 0, stream>>>(x, w1p, b1, regA);
  k_conv<16, 32, 64, 32, 8, 2, true, true, 68, true, 36, 4>
      <<<1024, 256, 0, stream>>>(regA, w2p, b2, regB);
  k_conv<32, 64, 32, 16, 4, 1, false, true, 36, false, 16, 16>
      <<<1024, 256, 0, stream>>>(regB, w3p, b3, ze);
  // vector quantization
  k_vq<<<4096, 256, 0, stream>>>(ze, cb, quant, regC);
  // decoder
  k_convt<64, 32, 16, 4, 1, 20, true, 36, 8>
      <<<512, 256, 0, stream>>>(regC, t1p, db1, regB);
  k_convt<32, 16, 32, 4, 1, 36, true, 68, 4>
      <<<2048, 256, 0, stream>>>(regB, t2p, db2, regA);
  k_convt3o<<<2048, 256, 0, stream>>>(regA, t3p, db3, xhat);
}

// Round 7
// 1273.460 us; speedup vs baseline: 1.2171x; 1.2171x over previous
//
#include <hip/hip_runtime.h>
#include <math.h>

// ---------------------------------------------------------------------------
// VQ-VAE 3D forward, round 7.
// Busy-time archaeology: r2 conv2 (ONE x4 weight tuple in flight per consume
// point) = 69us busy (1.26x FMA floor). r3-r6 (16-64 tuples exposed by full
// tap/channel unrolls, > SGPR file) = 216-218us busy across four different
// builds. Fix: every kernel consumes weights as 1-2 x4 scalar tuples feeding
// 8+ FMAs immediately, with static register-array indexing everywhere.
// ConvT weights repacked per-parity: Wp[ci][p][co][2][4+4pad] (32B gaps stop
// x8/x16 merging); forward conv uses natural OIDHW (c-stride non-contiguous).
// ---------------------------------------------------------------------------

__device__ __forceinline__ float4 ld4(const float* p) {
  float4 q; __builtin_memcpy(&q, p, 16); return q;
}
struct F3 { float x, y, z; };
__device__ __forceinline__ F3 ld3(const float* p) {
  F3 q; __builtin_memcpy(&q, p, 12); return q;
}

#define WAVES_HINT __attribute__((amdgpu_waves_per_eu(2, 4)))

// ---------------- convT weight repack: -> Wp[ci][p][co][2][8] ---------------
// src w[ci][co][kz*16+ky*4+kx] (PyTorch convT layout).
// For parity p=(pz,py,px) and octet-tap a=(az,ay,ax): k = 3-p-2a per axis.
// Slot: group g=az holds j=ay*2+ax in [0,4); slots 4..7 of each group unused.
template<int CIN, int COUT>
__global__ __launch_bounds__(256) void k_repackT(const float* __restrict__ w,
                                                 float* __restrict__ dst) {
  const int idx = blockIdx.x * 256 + threadIdx.x;
  if (idx >= CIN * 8 * COUT * 8) return;
  const int a  = idx & 7;
  const int co = (idx >> 3) % COUT;
  const int p  = ((idx >> 3) / COUT) & 7;
  const int ci = idx >> 3 >> 3; // / (COUT*8) only if COUT pow2 — compute safely:
  const int ci2 = idx / (8 * COUT * 8);
  (void)ci;
  const int az = a >> 2, ay = (a >> 1) & 1, ax = a & 1;
  const int pz = p >> 2, py = (p >> 1) & 1, px = p & 1;
  const int kz = 3 - pz - 2 * az, ky = 3 - py - 2 * ay, kx = 3 - px - 2 * ax;
  dst[(((size_t)(ci2 * 8 + p) * COUT + co) * 16) + az * 8 + (ay * 2 + ax)] =
      w[((size_t)ci2 * COUT + co) * 64 + (kz * 16 + ky * 4 + kx)];
}

// ---------------- halo zeroing for padded buffers ---------------------------
template<int S, int D, int NCH>
__global__ __launch_bounds__(256) void k_zhalo(float* __restrict__ buf) {
  const int vol = S * S * S;
  const long long idx = (long long)blockIdx.x * 256 + threadIdx.x;
  if (idx >= (long long)NCH * vol) return;
  const int r = (int)(idx % vol);
  const int z = r / (S * S), y = (r / S) % S, x = r % S;
  if (z < 1 || z > D || y < 1 || y > D || x < 1 || x > D) buf[idx] = 0.0f;
}

// ---------------- forward conv (k=4,s=2,p=1) --------------------------------
// Weights natural OIDHW; per c exactly one x4 tuple feeding 4*TZ FMAs.
template<int CIN, int COUT, int DIN, int DOUT, int OCG, int TZ, bool RELU,
         bool INP, int SIN, bool OUTP, int SOUT, int NG>
__global__ __launch_bounds__(256) WAVES_HINT
void k_conv(const float* __restrict__ xin, const float* __restrict__ wg,
            const float* __restrict__ bias, float* __restrict__ out) {
  constexpr int NBX = DOUT / 8, NBY = DOUT / 8, NBZ = DOUT / (4 * TZ);
  constexpr size_t VIN  = INP  ? (size_t)SIN * SIN * SIN : (size_t)DIN * DIN * DIN;
  constexpr size_t VOUT = OUTP ? (size_t)SOUT * SOUT * SOUT : (size_t)DOUT * DOUT * DOUT;
  const int tid = threadIdx.x;
  const int tx = tid & 7, ty = (tid >> 3) & 7, tz = tid >> 6;
  int bb = blockIdx.x;
  const int g  = bb % NG;  bb /= NG;
  const int gx = bb % NBX; bb /= NBX;
  const int gy = bb % NBY; bb /= NBY;
  const int gz = bb % NBZ; bb /= NBZ;
  const int b = bb;
  const int oc0 = g * OCG;
  const int ow = gx * 8 + tx, oh = gy * 8 + ty, od0 = gz * (4 * TZ) + tz;

  float acc[TZ][OCG];
#pragma unroll
  for (int j = 0; j < TZ; ++j)
#pragma unroll
    for (int c = 0; c < OCG; ++c) acc[j][c] = 0.0f;

#pragma unroll 1
  for (int ci = 0; ci < CIN; ++ci) {
    const float* xb = xin + (size_t)(b * CIN + ci) * VIN;
#pragma unroll 1
    for (int t16 = 0; t16 < 16; ++t16) {   // t16 = kd*4 + kh
      float4 q[TZ];
      if (INP) {
        const int zp = od0 * 2 + (t16 >> 2);
        const int yp = oh * 2 + (t16 & 3);
        const float* r0 = xb + ((size_t)zp * SIN + yp) * SIN + ow * 2;
#pragma unroll
        for (int j = 0; j < TZ; ++j) q[j] = ld4(r0 + (size_t)j * 8 * SIN * SIN);
      } else {
        const int y  = oh * 2 - 1 + (t16 & 3);
        const int x0 = ow * 2 - 1;
        const bool vy = (unsigned)y < (unsigned)DIN;
#pragma unroll
        for (int j = 0; j < TZ; ++j) {
          const int z = od0 * 2 - 1 + (t16 >> 2) + j * 8;
          const bool vz = vy && ((unsigned)z < (unsigned)DIN);
          const float* xr = xb + ((size_t)z * DIN + y) * DIN + x0;
          q[j].x = (vz && (unsigned)(x0 + 0) < (unsigned)DIN) ? xr[0] : 0.0f;
          q[j].y = (vz && (unsigned)(x0 + 1) < (unsigned)DIN) ? xr[1] : 0.0f;
          q[j].z = (vz && (unsigned)(x0 + 2) < (unsigned)DIN) ? xr[2] : 0.0f;
          q[j].w = (vz && (unsigned)(x0 + 3) < (unsigned)DIN) ? xr[3] : 0.0f;
        }
      }
#pragma unroll
      for (int c = 0; c < OCG; ++c) {
        // one x4 tuple in flight per consume point (r2's measured-clean shape)
        const float4 w4 = ld4(wg + ((size_t)(oc0 + c) * CIN + ci) * 64 + t16 * 4);
#pragma unroll
        for (int j = 0; j < TZ; ++j) {
          acc[j][c] = fmaf(q[j].x, w4.x, acc[j][c]);
          acc[j][c] = fmaf(q[j].y, w4.y, acc[j][c]);
          acc[j][c] = fmaf(q[j].z, w4.z, acc[j][c]);
          acc[j][c] = fmaf(q[j].w, w4.w, acc[j][c]);
        }
      }
    }
  }

#pragma unroll
  for (int c = 0; c < OCG; ++c) {
    const float bv = bias[oc0 + c];
#pragma unroll
    for (int j = 0; j < TZ; ++j) {
      float v = acc[j][c] + bv;
      if (RELU) v = fmaxf(v, 0.0f);
      const int od = od0 + j * 4;
      if (OUTP)
        out[(size_t)(b * COUT + oc0 + c) * VOUT
            + ((size_t)(od + 1) * SOUT + (oh + 1)) * SOUT + (ow + 1)] = v;
      else
        out[(size_t)(b * COUT + oc0 + c) * VOUT
            + ((size_t)od * DOUT + oh) * DOUT + ow] = v;
    }
  }
}

// ---------------- transposed conv (k=4,s=2,p=1), octet-per-thread -----------
// Weights via per-parity repack Wp[ci][p][co][2][8]: per (p,c) exactly two x4
// tuples feeding 8 FMAs with static xn indices. EPI: 0 none, 1 relu, 2 sigm.
template<int CIN, int COUT, int DIN, int OCG, int EPI, int SIN,
         bool OUTP, int SOUT, int NG>
__global__ __launch_bounds__(256) WAVES_HINT
void k_convt(const float* __restrict__ xin, const float* __restrict__ wp,
             const float* __restrict__ bias, float* __restrict__ out) {
  constexpr int DOUT = 2 * DIN, NBX = DIN / 8, NBY = DIN / 8, NBZ = DIN / 4;
  constexpr size_t VIN  = (size_t)SIN * SIN * SIN;
  constexpr size_t VOUT = OUTP ? (size_t)SOUT * SOUT * SOUT
                               : (size_t)DOUT * DOUT * DOUT;
  const int tid = threadIdx.x;
  const int tx = tid & 7, ty = (tid >> 3) & 7, tz = tid >> 6;
  int bb = blockIdx.x;
  const int g  = bb % NG;  bb /= NG;
  const int gx = bb % NBX; bb /= NBX;
  const int gy = bb % NBY; bb /= NBY;
  const int gz = bb % NBZ; bb /= NBZ;
  const int b = bb;
  const int oc0 = g * OCG;
  const int mx = gx * 8 + tx, my = gy * 8 + ty, mz = gz * 4 + tz;

  float acc[8][OCG];
#pragma unroll
  for (int p = 0; p < 8; ++p)
#pragma unroll
    for (int c = 0; c < OCG; ++c) acc[p][c] = 0.0f;

#pragma unroll 1
  for (int ci = 0; ci < CIN; ++ci) {
    const float* xb = xin + (size_t)(b * CIN + ci) * VIN
                          + ((size_t)mz * SIN + my) * SIN + mx;
    float xn[3][3][3];
#pragma unroll
    for (int dz = 0; dz < 3; ++dz)
#pragma unroll
      for (int dy = 0; dy < 3; ++dy) {
        const F3 t = ld3(xb + ((size_t)dz * SIN + dy) * SIN);
        xn[dz][dy][0] = t.x; xn[dz][dy][1] = t.y; xn[dz][dy][2] = t.z;
      }
    const float* wci = wp + (size_t)ci * 8 * COUT * 16;
#pragma unroll
    for (int p = 0; p < 8; ++p) {
      const int pz = p >> 2, py = (p >> 1) & 1, px = p & 1;
#pragma unroll
      for (int c = 0; c < OCG; ++c) {
        const float* wb = wci + ((size_t)p * COUT + (oc0 + c)) * 16;
        const float4 wA = ld4(wb);      // az=0 taps (j = ay*2+ax)
        const float4 wB = ld4(wb + 8);  // az=1 taps
        acc[p][c] = fmaf(xn[pz    ][py    ][px    ], wA.x, acc[p][c]);
        acc[p][c] = fmaf(xn[pz    ][py    ][px + 1], wA.y, acc[p][c]);
        acc[p][c] = fmaf(xn[pz    ][py + 1][px    ], wA.z, acc[p][c]);
        acc[p][c] = fmaf(xn[pz    ][py + 1][px + 1], wA.w, acc[p][c]);
        acc[p][c] = fmaf(xn[pz + 1][py    ][px    ], wB.x, acc[p][c]);
        acc[p][c] = fmaf(xn[pz + 1][py    ][px + 1], wB.y, acc[p][c]);
        acc[p][c] = fmaf(xn[pz + 1][py + 1][px    ], wB.z, acc[p][c]);
        acc[p][c] = fmaf(xn[pz + 1][py + 1][px + 1], wB.w, acc[p][c]);
      }
    }
  }

#pragma unroll
  for (int c = 0; c < OCG; ++c) {
    const float bv = bias[oc0 + c];
#pragma unroll
    for (int p = 0; p < 8; ++p) {
      const int pz = p >> 2, py = (p >> 1) & 1, px = p & 1;
      float v = acc[p][c] + bv;
      if (EPI == 1) v = fmaxf(v, 0.0f);
      if (EPI == 2) v = 1.0f / (1.0f + expf(-v));
      if (OUTP)
        out[(size_t)(b * COUT + oc0 + c) * VOUT
            + ((size_t)(2 * mz + pz + 1) * SOUT + (2 * my + py + 1)) * SOUT
            + (2 * mx + px + 1)] = v;
      else
        out[(size_t)(b * COUT + oc0 + c) * VOUT
            + ((size_t)(2 * mz + pz) * DOUT + (2 * my + py)) * DOUT
            + (2 * mx + px)] = v;
    }
  }
}

// ---------------- VQ: argmin over 512 codes, gather codebook ----------------
__global__ __launch_bounds__(256) void k_vq(const float* __restrict__ ze,
                                            const float* __restrict__ cb,
                                            float* __restrict__ quant,
                                            float* __restrict__ quantp) {
  __shared__ float ct[64 * 65];
  __shared__ float zs[4][64];
  __shared__ int   bis[4];
  const int tid  = threadIdx.x;
  const int lane = tid & 63;
  const int wv   = tid >> 6;
  const int p0 = blockIdx.x * 4;
  const int b  = p0 >> 12;
  const int n0 = p0 & 4095;

  {
    const int c = tid >> 2, j = tid & 3;
    zs[j][c] = ze[((size_t)(b * 64 + c) << 12) + n0 + j];
  }

  float best = 3.4e38f;
  int bi = 0;
#pragma unroll 1
  for (int ch = 0; ch < 8; ++ch) {
    __syncthreads();
    for (int i = tid; i < 4096; i += 256) {
      const int r = i >> 6, c = i & 63;
      ct[r * 65 + c] = cb[((ch * 64 + r) << 6) + c];
    }
    __syncthreads();
    float d = 0.0f;
#pragma unroll 8
    for (int c = 0; c < 64; ++c) {
      const float t = zs[wv][c] - ct[lane * 65 + c];
      d = fmaf(t, t, d);
    }
    const int k = ch * 64 + lane;
    if (d < best) { best = d; bi = k; }
  }
#pragma unroll
  for (int off = 32; off > 0; off >>= 1) {
    const float ob = __shfl_down(best, off);
    const int   oi = __shfl_down(bi, off);
    if (ob < best || (ob == best && oi < bi)) { best = ob; bi = oi; }
  }
  if (lane == 0) bis[wv] = bi;
  __syncthreads();
  {
    const int c = tid >> 2, j = tid & 3;
    const float val = cb[(bis[j] << 6) + c];
    const int n = n0 + j;
    quant[((size_t)(b * 64 + c) << 12) + n] = val;
    const int zz = n >> 8, yy = (n >> 4) & 15, xx = n & 15;
    quantp[(size_t)(b * 64 + c) * 8000
           + ((size_t)(zz + 1) * 20 + (yy + 1)) * 20 + (xx + 1)] = val;
  }
}

// ---------------------------------------------------------------------------
extern "C" void kernel_launch(void* const* d_in, const int* in_sizes, int n_in,
                              void* d_out, int out_size, void* d_ws, size_t ws_size,
                              hipStream_t stream) {
  const float* x   = (const float*)d_in[0];
  const float* w1  = (const float*)d_in[1];
  const float* b1  = (const float*)d_in[2];
  const float* w2  = (const float*)d_in[3];
  const float* b2  = (const float*)d_in[4];
  const float* w3  = (const float*)d_in[5];
  const float* b3  = (const float*)d_in[6];
  const float* cb  = (const float*)d_in[7];
  const float* dw1 = (const float*)d_in[8];
  const float* db1 = (const float*)d_in[9];
  const float* dw2 = (const float*)d_in[10];
  const float* db2 = (const float*)d_in[11];
  const float* dw3 = (const float*)d_in[12];
  const float* db3 = (const float*)d_in[13];

  float* outf  = (float*)d_out;
  float* xhat  = outf;               // [4,1,128^3]
  float* quant = outf + 8388608;     // [4,64,16^3]
  float* ze    = outf + 9437184;     // [4,64,16^3]

  // workspace layout
  float* regA = (float*)d_ws;                        // 64 x 68^3 (y1, d2)
  float* regB = regA + (size_t)64 * 68 * 68 * 68;    // 128 x 36^3 (y2, d1)
  float* regC = regB + (size_t)128 * 36 * 36 * 36;   // 256 x 20^3 (quantp)
  float* t1p = regC + (size_t)256 * 20 * 20 * 20;    // 64*8*32*16 = 262144
  float* t2p = t1p + 262144;                         // 32*8*16*16 = 65536
  float* t3p = t2p + 65536;                          // 16*8*1*16  = 2048

  // convT weight repacks + halo zeroing (ws re-poisoned every launch)
  k_repackT<64, 32><<<512, 256, 0, stream>>>(dw1, t1p);
  k_repackT<32, 16><<<128, 256, 0, stream>>>(dw2, t2p);
  k_repackT<16, 1><<<4, 256, 0, stream>>>(dw3, t3p);
  k_zhalo<68, 64, 64><<<78608, 256, 0, stream>>>(regA);
  k_zhalo<36, 32, 128><<<23328, 256, 0, stream>>>(regB);
  k_zhalo<20, 16, 256><<<8000, 256, 0, stream>>>(regC);

  // encoder
  k_conv<1, 16, 128, 64, 16, 2, true, false, 0, true, 68, 1>
      <<<2048, 256, 0, stream>>>(x, w1, b1, regA);
  k_conv<16, 32, 64, 32, 16, 1, true, true, 68, true, 36, 2>
      <<<1024, 256, 0, stream>>>(regA, w2, b2, regB);
  k_conv<32, 64, 32, 16, 4, 1, false, true, 36, false, 16, 16>
      <<<1024, 256, 0, stream>>>(regB, w3, b3, ze);
  // vector quantization
  k_vq<<<4096, 256, 0, stream>>>(ze, cb, quant, regC);
  // decoder
  k_convt<64, 32, 16, 2, 1, 20, true, 36, 16>
      <<<1024, 256, 0, stream>>>(regC, t1p, db1, regB);
  k_convt<32, 16, 32, 2, 1, 36, true, 68, 8>
      <<<4096, 256, 0, stream>>>(regB, t2p, db2, regA);
  k_convt<16, 1, 64, 1, 2, 68, false, 0, 1>
      <<<4096, 256, 0, stream>>>(regA, t3p, db3, xhat);
}